// Round 7
// baseline (83.775 us; speedup 1.0000x reference)
//
#include <hip/hip_runtime.h>

// SADecompLayer: per-channel, per-8x8-block dihedral symmetrization.
//   s = b + fliplr(b) + flipud(b) + fliplr(flipud(b))   (flip-invariant)
//   out = (s + rot90_ccw(s)) / 8
// S[a][b] (a,b in 0..3) = b[a][b]+b[a][7-b]+b[7-a][b]+b[7-a][7-b]
// out[i][j] = (S[m(i)][m(j)] + S[m(j)][m(i)]) * 0.125,  m(i)=min(i,7-i)
//
// Layout: TWO lanes per 8x8 block (lane parity = left/right 4-col half) so
// every global load/store is 64 lanes x consecutive float4 = 1 KiB coalesced.
// Vertical fold lane-local; horizontal fold via __shfl_xor(.,1) (DPP).
//
// Cache policy experiment (R7): INVERTED vs R3-R6. 512 MiB crosses the kernel
// per replay but L3 = 256 MiB; the allocation policy picks which stream pays
// HBM. Here: NONTEMPORAL LOADS (input never allocates in MALL) + NORMAL
// stores (output owns L3). If the MALL is writeback, steady-state replays
// re-dirty the same resident output lines -> WRITE_SIZE ~ 0, and HBM carries
// only the 268 MB input read stream (~7 TB/s read rate) -> ~45-60 us.
// Loads are coherence-safe (no R4-style stale-store hazard).
//   R4 NOTE still holds: never use sc1/write-through asm stores here.

constexpr int KW = 8;
constexpr int W  = 1024;
constexpr int W4 = W / 4;       // 256 float4 per image row
constexpr int WB = W / KW;      // 128 block-columns
constexpr int ITERS = 4;

typedef float v4f __attribute__((ext_vector_type(4)));

__device__ __forceinline__ int half_block_base(int t) {
    // t = half-block index; returns float4 index of its (row0, col0)
    int half = t & 1;
    int blk  = t >> 1;
    int bx   = blk & (WB - 1);
    int rest = blk >> 7;              // channel*hb + block-row
    return rest * (KW * W4) + bx * 2 + half;
}

__global__ __launch_bounds__(256) void sadecomp_kernel(
    const float* __restrict__ in, float* __restrict__ out) {
    const int t0     = blockIdx.x * blockDim.x + threadIdx.x;
    const int stride = gridDim.x * blockDim.x;          // even -> parity fixed
    const bool rightHalf = (t0 & 1) != 0;

    const v4f* __restrict__ inp  = reinterpret_cast<const v4f*>(in);
    v4f* __restrict__       outp = reinterpret_cast<v4f*>(out);

    v4f cur[8];
    int base = half_block_base(t0);
#pragma unroll
    for (int r = 0; r < 8; ++r)
        cur[r] = __builtin_nontemporal_load(&inp[base + r * W4]);

#pragma unroll
    for (int k = 0; k < ITERS; ++k) {
        // prefetch next iteration's 8 rows before touching cur
        v4f nxt[8];
        int nbase = 0;
        if (k + 1 < ITERS) {
            nbase = half_block_base(t0 + (k + 1) * stride);
#pragma unroll
            for (int r = 0; r < 8; ++r)
                nxt[r] = __builtin_nontemporal_load(&inp[nbase + r * W4]);
        }

        // vertical fold: wv[a] = row a + row 7-a  (lane-local)
        v4f wv[4];
#pragma unroll
        for (int a = 0; a < 4; ++a) wv[a] = cur[a] + cur[7 - a];

        // horizontal fold with partner lane (lane^1): u[a][b] = wv[a][b]+p[a][3-b]
        float u[4][4];
#pragma unroll
        for (int a = 0; a < 4; ++a) {
            float px = __shfl_xor(wv[a].x, 1);
            float py = __shfl_xor(wv[a].y, 1);
            float pz = __shfl_xor(wv[a].z, 1);
            float pw = __shfl_xor(wv[a].w, 1);
            u[a][0] = wv[a].x + pw;
            u[a][1] = wv[a].y + pz;
            u[a][2] = wv[a].z + py;
            u[a][3] = wv[a].w + px;
        }

        // symmetrize; second operand index differs per half (v_cndmask)
        float T[4][4];
#pragma unroll
        for (int a = 0; a < 4; ++a) {
#pragma unroll
            for (int b = 0; b < 4; ++b) {
                float second = rightHalf ? u[3 - b][3 - a] : u[b][a];
                T[a][b] = (u[a][b] + second) * 0.125f;
            }
        }

        // rows i and 7-i identical; 8 coalesced NORMAL row stores
        // (output should allocate + stay resident in L3)
#pragma unroll
        for (int i = 0; i < 4; ++i) {
            v4f o;
            o.x = T[i][0]; o.y = T[i][1]; o.z = T[i][2]; o.w = T[i][3];
            outp[base + i * W4]       = o;
            outp[base + (7 - i) * W4] = o;
        }

        base = nbase;
#pragma unroll
        for (int r = 0; r < 8; ++r) cur[r] = nxt[r];
    }
}

extern "C" void kernel_launch(void* const* d_in, const int* in_sizes, int n_in,
                              void* d_out, int out_size, void* d_ws, size_t ws_size,
                              hipStream_t stream) {
    const float* in = (const float*)d_in[0];
    float* out = (float*)d_out;

    // mat: (1, 64, 1024, 1024) f32 -> 64*128*128 blocks, 2 half-lanes each
    const int nhalf = (out_size / (KW * KW)) * 2;       // 2,097,152
    const int block = 256;
    const int grid = nhalf / (block * ITERS);           // 2048 (exact)
    sadecomp_kernel<<<grid, block, 0, stream>>>(in, out);
}

// Round 8
// 81.522 us; speedup vs baseline: 1.0276x; 1.0276x over previous
//
#include <hip/hip_runtime.h>

// SADecompLayer: per-channel, per-8x8-block dihedral symmetrization.
//   s = b + fliplr(b) + flipud(b) + fliplr(flipud(b))   (flip-invariant)
//   out = (s + rot90_ccw(s)) / 8
// S[a][b] (a,b in 0..3) = b[a][b]+b[a][7-b]+b[7-a][b]+b[7-a][7-b]
// out[i][j] = (S[m(i)][m(j)] + S[m(j)][m(i)]) * 0.125,  m(i)=min(i,7-i)
//
// Final configuration (best measured, 81.6 us):
// - TWO lanes per 8x8 block (lane parity = left/right half): every global
//   load/store is 64 lanes x consecutive float4 = 1 KiB coalesced.
// - Vertical fold lane-local; horizontal fold via __shfl_xor(.,1) (DPP).
// - NONTEMPORAL STORES (__builtin_nontemporal_store, L2-coherent `nt`):
//   output (never re-read) evict-first -> input stays half L3-resident
//   across graph replays. Measured FETCH 268->134 MB, 100->82 us.
// - ITERS=4 persistent grid with register double-buffering (neutral but
//   not harmful; keeps launch churn low).
//
// Measured policy space (do not revisit):
// - sc1/write-through asm stores: INCORRECT (lose to harness's dirty
//   memset lines in L2 — R4 failure, absmax ~= max|ref|).
// - nt loads + normal stores (L3-for-output): 83.8 us — MALL does not
//   retain re-dirtied output across replays (R7).
// - 1 lane/block (32B-stride access): 114 us (R1). Naive: n/a.

constexpr int KW = 8;
constexpr int W  = 1024;
constexpr int W4 = W / 4;       // 256 float4 per image row
constexpr int WB = W / KW;      // 128 block-columns
constexpr int ITERS = 4;

typedef float v4f __attribute__((ext_vector_type(4)));

__device__ __forceinline__ int half_block_base(int t) {
    // t = half-block index; returns float4 index of its (row0, col0)
    int half = t & 1;
    int blk  = t >> 1;
    int bx   = blk & (WB - 1);
    int rest = blk >> 7;              // channel*hb + block-row
    return rest * (KW * W4) + bx * 2 + half;
}

__global__ __launch_bounds__(256) void sadecomp_kernel(
    const float* __restrict__ in, float* __restrict__ out) {
    const int t0     = blockIdx.x * blockDim.x + threadIdx.x;
    const int stride = gridDim.x * blockDim.x;          // even -> parity fixed
    const bool rightHalf = (t0 & 1) != 0;

    const v4f* __restrict__ inp  = reinterpret_cast<const v4f*>(in);
    v4f* __restrict__       outp = reinterpret_cast<v4f*>(out);

    v4f cur[8];
    int base = half_block_base(t0);
#pragma unroll
    for (int r = 0; r < 8; ++r) cur[r] = inp[base + r * W4];

#pragma unroll
    for (int k = 0; k < ITERS; ++k) {
        // prefetch next iteration's 8 rows before touching cur
        v4f nxt[8];
        int nbase = 0;
        if (k + 1 < ITERS) {
            nbase = half_block_base(t0 + (k + 1) * stride);
#pragma unroll
            for (int r = 0; r < 8; ++r) nxt[r] = inp[nbase + r * W4];
        }

        // vertical fold: wv[a] = row a + row 7-a  (lane-local)
        v4f wv[4];
#pragma unroll
        for (int a = 0; a < 4; ++a) wv[a] = cur[a] + cur[7 - a];

        // horizontal fold with partner lane (lane^1): u[a][b] = wv[a][b]+p[a][3-b]
        float u[4][4];
#pragma unroll
        for (int a = 0; a < 4; ++a) {
            float px = __shfl_xor(wv[a].x, 1);
            float py = __shfl_xor(wv[a].y, 1);
            float pz = __shfl_xor(wv[a].z, 1);
            float pw = __shfl_xor(wv[a].w, 1);
            u[a][0] = wv[a].x + pw;
            u[a][1] = wv[a].y + pz;
            u[a][2] = wv[a].z + py;
            u[a][3] = wv[a].w + px;
        }

        // symmetrize; second operand index differs per half (v_cndmask)
        float T[4][4];
#pragma unroll
        for (int a = 0; a < 4; ++a) {
#pragma unroll
            for (int b = 0; b < 4; ++b) {
                float second = rightHalf ? u[3 - b][3 - a] : u[b][a];
                T[a][b] = (u[a][b] + second) * 0.125f;
            }
        }

        // rows i and 7-i identical; 8 coalesced nontemporal row stores
#pragma unroll
        for (int i = 0; i < 4; ++i) {
            v4f o;
            o.x = T[i][0]; o.y = T[i][1]; o.z = T[i][2]; o.w = T[i][3];
            __builtin_nontemporal_store(o, &outp[base + i * W4]);
            __builtin_nontemporal_store(o, &outp[base + (7 - i) * W4]);
        }

        base = nbase;
#pragma unroll
        for (int r = 0; r < 8; ++r) cur[r] = nxt[r];
    }
}

extern "C" void kernel_launch(void* const* d_in, const int* in_sizes, int n_in,
                              void* d_out, int out_size, void* d_ws, size_t ws_size,
                              hipStream_t stream) {
    const float* in = (const float*)d_in[0];
    float* out = (float*)d_out;

    // mat: (1, 64, 1024, 1024) f32 -> 64*128*128 blocks, 2 half-lanes each
    const int nhalf = (out_size / (KW * KW)) * 2;       // 2,097,152
    const int block = 256;
    const int grid = nhalf / (block * ITERS);           // 2048 (exact)
    sadecomp_kernel<<<grid, block, 0, stream>>>(in, out);
}